// Round 2
// baseline (819.986 us; speedup 1.0000x reference)
//
#include <hip/hip_runtime.h>

#define CDIM 512
#define NDIM 4096
#define BATCH 4

using bf8v = __attribute__((ext_vector_type(8))) __bf16;
using f4v  = __attribute__((ext_vector_type(4))) float;

static __device__ __forceinline__ unsigned short f2bf(float f) {
  unsigned int u = __float_as_uint(f);
  u += 0x7fffu + ((u >> 16) & 1u);   // round-to-nearest-even
  return (unsigned short)(u >> 16);
}

// ---------------- GN pass 1: per-(b,g) mean/rstd ----------------
// One block per (b,g); group = contiguous 16ch x 4096 = 65536 fp32.
__global__ __launch_bounds__(256) void gn_stats_kernel(
    const float* __restrict__ x, float* __restrict__ stats) {
  const int tid = threadIdx.x;
  const float4* xv = (const float4*)(x + (long)blockIdx.x * 65536);
  float s = 0.f, ss = 0.f;
  for (int i = tid; i < 16384; i += 256) {
    float4 d = xv[i];
    s  += d.x + d.y + d.z + d.w;
    ss += d.x * d.x + d.y * d.y + d.z * d.z + d.w * d.w;
  }
#pragma unroll
  for (int off = 32; off; off >>= 1) {
    s  += __shfl_down(s, off);
    ss += __shfl_down(ss, off);
  }
  __shared__ float red[8];
  if ((tid & 63) == 0) { red[tid >> 6] = s; red[4 + (tid >> 6)] = ss; }
  __syncthreads();
  if (tid == 0) {
    float S  = red[0] + red[1] + red[2] + red[3];
    float SS = red[4] + red[5] + red[6] + red[7];
    float mean = S * (1.f / 65536.f);
    float var  = SS * (1.f / 65536.f) - mean * mean;
    stats[blockIdx.x * 2]     = mean;
    stats[blockIdx.x * 2 + 1] = rsqrtf(var + 1e-6f);
  }
}

// ---------------- GN pass 2: normalize + transpose, fp32 [C,N] -> bf16 [N,C] ----------------
__global__ __launch_bounds__(256) void gn_transpose_kernel(
    const float* __restrict__ x, const float* __restrict__ gs,
    const float* __restrict__ gb, const float* __restrict__ stats,
    unsigned short* __restrict__ hT) {
  __shared__ float t[64][65];
  const int tid = threadIdx.x;
  const int b = blockIdx.z;
  const long bbx = (long)b * ((long)CDIM * NDIM);
  const int n0 = blockIdx.x * 64, c0 = blockIdx.y * 64;
  for (int k = 0; k < 4; ++k) {
    int it = tid + k * 256;          // 1024 items: 64 ch x 16 float4
    int c = it >> 4, no = (it & 15) << 2;
    int ch = c0 + c;
    int g = ch >> 4;
    float mean = stats[(b * 32 + g) * 2];
    float rstd = stats[(b * 32 + g) * 2 + 1];
    float a  = rstd * gs[ch];
    float bb = gb[ch] - mean * a;
    float4 d = *(const float4*)&x[bbx + (long)ch * NDIM + n0 + no];
    t[no + 0][c] = d.x * a + bb;
    t[no + 1][c] = d.y * a + bb;
    t[no + 2][c] = d.z * a + bb;
    t[no + 3][c] = d.w * a + bb;
  }
  __syncthreads();
  const long bbh = (long)b * ((long)NDIM * CDIM);
  for (int k = 0; k < 2; ++k) {
    int it = tid + k * 256;          // 512 items: 64 n x 8 groups-of-8
    int n = it >> 3, co = (it & 7) << 3;
    unsigned int ow[4];
#pragma unroll
    for (int j = 0; j < 4; ++j) {
      unsigned short lo = f2bf(t[n][co + 2 * j]);
      unsigned short hi = f2bf(t[n][co + 2 * j + 1]);
      ow[j] = (unsigned int)lo | ((unsigned int)hi << 16);
    }
    uint4 o; o.x = ow[0]; o.y = ow[1]; o.z = ow[2]; o.w = ow[3];
    *(uint4*)&hT[bbh + (long)(n0 + n) * CDIM + c0 + co] = o;
  }
}

// ---------------- fp32 -> bf16 convert (weights) ----------------
__global__ __launch_bounds__(256) void cvt_kernel(
    const float* __restrict__ src, unsigned short* __restrict__ dst, int n4) {
  int i = blockIdx.x * 256 + threadIdx.x;
  if (i >= n4) return;
  float4 d = ((const float4*)src)[i];
  ushort4 o;
  o.x = f2bf(d.x); o.y = f2bf(d.y); o.z = f2bf(d.z); o.w = f2bf(d.w);
  ((ushort4*)dst)[i] = o;
}

// ---------------- NT GEMM: C[M,Nn] = A[M,K] * B[Nn,K]^T (both K-contiguous, bf16) ----------------
// EPI: 0 = bf16 + bias[col]   (qT/kT)
//      1 = bf16 + bias[row]   (v)
//      2 = fp32 * 512^-0.5    (scores)
//      3 = bf16 plain         (attn @ v -> OT)
//      4 = fp32 + bias[row] + residual X (proj -> d_out)
#define BM 128
#define BN 128
#define BK 32
#define LDSP 40  // BK + 8 pad: 80B row stride -> 2-way bank alias only (free per m136)

template <int EPI>
__global__ __launch_bounds__(256) void gemm_nt(
    const unsigned short* __restrict__ A, long sA,
    const unsigned short* __restrict__ B, long sB,
    void* __restrict__ Cp, long sC,
    const float* __restrict__ bias,
    const float* __restrict__ X, long sX,
    int M, int Nn, int K) {
  __shared__ unsigned short As[BM * LDSP];
  __shared__ unsigned short Bs[BN * LDSP];
  const int tid = threadIdx.x;
  const int z = blockIdx.z;
  A += (long)z * sA;
  B += (long)z * sB;
  const int m0 = blockIdx.y * BM;
  const int n0 = blockIdx.x * BN;
  const int lane = tid & 63;
  const int wave = tid >> 6;
  const int wm = (wave >> 1) << 6;
  const int wn = (wave & 1) << 6;
  const int l16 = lane & 15;
  const int quad = lane >> 4;

  f4v acc[4][4] = {};

  for (int k0 = 0; k0 < K; k0 += BK) {
#pragma unroll
    for (int it = 0; it < 2; ++it) {
      int item = tid + (it << 8);
      int r = item >> 2;
      int kc = (item & 3) << 3;
      *(uint4*)&As[r * LDSP + kc] = *(const uint4*)&A[(long)(m0 + r) * K + k0 + kc];
      *(uint4*)&Bs[r * LDSP + kc] = *(const uint4*)&B[(long)(n0 + r) * K + k0 + kc];
    }
    __syncthreads();
    bf8v af[4], bv_[4];
#pragma unroll
    for (int t = 0; t < 4; ++t) {
      af[t]  = *(const bf8v*)&As[(wm + t * 16 + l16) * LDSP + quad * 8];
      bv_[t] = *(const bf8v*)&Bs[(wn + t * 16 + l16) * LDSP + quad * 8];
    }
#pragma unroll
    for (int tm = 0; tm < 4; ++tm)
#pragma unroll
      for (int tn = 0; tn < 4; ++tn)
        acc[tm][tn] = __builtin_amdgcn_mfma_f32_16x16x32_bf16(af[tm], bv_[tn], acc[tm][tn], 0, 0, 0);
    __syncthreads();
  }

  // C/D layout (verified m89/m91): col = lane&15, row = quad*4 + reg
#pragma unroll
  for (int tm = 0; tm < 4; ++tm) {
#pragma unroll
    for (int tn = 0; tn < 4; ++tn) {
      const int col = n0 + wn + tn * 16 + l16;
#pragma unroll
      for (int r = 0; r < 4; ++r) {
        const int row = m0 + wm + tm * 16 + quad * 4 + r;
        float val = acc[tm][tn][r];
        if (EPI == 0) {
          val += bias[col];
          ((unsigned short*)Cp)[(long)z * sC + (long)row * Nn + col] = f2bf(val);
        } else if (EPI == 1) {
          val += bias[row];
          ((unsigned short*)Cp)[(long)z * sC + (long)row * Nn + col] = f2bf(val);
        } else if (EPI == 2) {
          ((float*)Cp)[(long)z * sC + (long)row * Nn + col] = val * 0.044194173824159216f;
        } else if (EPI == 3) {
          ((unsigned short*)Cp)[(long)z * sC + (long)row * Nn + col] = f2bf(val);
        } else {
          ((float*)Cp)[(long)z * sC + (long)row * Nn + col] =
              val + bias[row] + X[(long)z * sX + (long)row * Nn + col];
        }
      }
    }
  }
}

// ---------------- Row softmax: fp32 scores row -> bf16 attn row ----------------
__global__ __launch_bounds__(256) void softmax_kernel(
    const float* __restrict__ S, unsigned short* __restrict__ P) {
  const int tid = threadIdx.x;
  const float4* sv = (const float4*)(S + (long)blockIdx.x * NDIM);
  float4 v[4];
  float mx = -3.4e38f;
#pragma unroll
  for (int it = 0; it < 4; ++it) {
    v[it] = sv[it * 256 + tid];
    mx = fmaxf(mx, fmaxf(fmaxf(v[it].x, v[it].y), fmaxf(v[it].z, v[it].w)));
  }
#pragma unroll
  for (int off = 32; off; off >>= 1) mx = fmaxf(mx, __shfl_xor(mx, off));
  __shared__ float red[8];
  if ((tid & 63) == 0) red[tid >> 6] = mx;
  __syncthreads();
  mx = fmaxf(fmaxf(red[0], red[1]), fmaxf(red[2], red[3]));
  float sum = 0.f;
#pragma unroll
  for (int it = 0; it < 4; ++it) {
    v[it].x = __expf(v[it].x - mx);
    v[it].y = __expf(v[it].y - mx);
    v[it].z = __expf(v[it].z - mx);
    v[it].w = __expf(v[it].w - mx);
    sum += v[it].x + v[it].y + v[it].z + v[it].w;
  }
#pragma unroll
  for (int off = 32; off; off >>= 1) sum += __shfl_xor(sum, off);
  if ((tid & 63) == 0) red[4 + (tid >> 6)] = sum;
  __syncthreads();
  sum = red[4] + red[5] + red[6] + red[7];
  const float inv = 1.f / sum;
  unsigned short* Pr = P + (long)blockIdx.x * NDIM;
#pragma unroll
  for (int it = 0; it < 4; ++it) {
    int idx = (it * 256 + tid) * 4;
    ushort4 o;
    o.x = f2bf(v[it].x * inv);
    o.y = f2bf(v[it].y * inv);
    o.z = f2bf(v[it].z * inv);
    o.w = f2bf(v[it].w * inv);
    *(ushort4*)&Pr[idx] = o;
  }
}

extern "C" void kernel_launch(void* const* d_in, const int* in_sizes, int n_in,
                              void* d_out, int out_size, void* d_ws, size_t ws_size,
                              hipStream_t stream) {
  (void)in_sizes; (void)n_in; (void)out_size;
  const float* x  = (const float*)d_in[0];
  const float* gs = (const float*)d_in[1];
  const float* gb = (const float*)d_in[2];
  const float* wq = (const float*)d_in[3];
  const float* bq = (const float*)d_in[4];
  const float* wk = (const float*)d_in[5];
  const float* bk = (const float*)d_in[6];
  const float* wv = (const float*)d_in[7];
  const float* bv = (const float*)d_in[8];
  const float* wp = (const float*)d_in[9];
  const float* bp = (const float*)d_in[10];
  float* out = (float*)d_out;

  char* ws = (char*)d_ws;
  const long NC  = (long)NDIM * CDIM;   // per-batch [N,C] elems
  const long NCB = NC * 2 * BATCH;      // bytes per [B,N,C] bf16 buffer = 16,777,216
  const long NN  = (long)NDIM * NDIM;   // per-batch scores elems
  const long WB  = (long)CDIM * CDIM * 2;  // bf16 weight bytes = 524,288

  unsigned short* hT  = (unsigned short*)(ws);
  unsigned short* qT  = (unsigned short*)(ws + NCB);
  unsigned short* kT  = (unsigned short*)(ws + NCB * 2);
  unsigned short* vB  = (unsigned short*)(ws + NCB * 3);
  unsigned short* OT  = (unsigned short*)(ws + NCB * 4);
  unsigned short* wqb = (unsigned short*)(ws + NCB * 5);
  unsigned short* wkb = (unsigned short*)(ws + NCB * 5 + WB);
  unsigned short* wvb = (unsigned short*)(ws + NCB * 5 + WB * 2);
  unsigned short* wpb = (unsigned short*)(ws + NCB * 5 + WB * 3);
  float* stats        = (float*)(ws + NCB * 5 + WB * 4);
  char* dyn = ws + NCB * 5 + WB * 4 + 4096;   // base = 85,987,328
  const size_t base = (size_t)(NCB * 5 + WB * 4 + 4096);

  gn_stats_kernel<<<BATCH * 32, 256, 0, stream>>>(x, stats);
  gn_transpose_kernel<<<dim3(NDIM / 64, CDIM / 64, BATCH), 256, 0, stream>>>(x, gs, gb, stats, hT);
  cvt_kernel<<<256, 256, 0, stream>>>(wq, wqb, 65536);
  cvt_kernel<<<256, 256, 0, stream>>>(wk, wkb, 65536);
  cvt_kernel<<<256, 256, 0, stream>>>(wv, wvb, 65536);
  cvt_kernel<<<256, 256, 0, stream>>>(wp, wpb, 65536);

  // qT = hT*wq^T + bq ; kT = hT*wk^T + bk  ([N,C] out)
  gemm_nt<0><<<dim3(CDIM / BN, NDIM / BM, BATCH), 256, 0, stream>>>(
      hT, NC, wqb, 0, qT, NC, bq, nullptr, 0, NDIM, CDIM, CDIM);
  gemm_nt<0><<<dim3(CDIM / BN, NDIM / BM, BATCH), 256, 0, stream>>>(
      hT, NC, wkb, 0, kT, NC, bk, nullptr, 0, NDIM, CDIM, CDIM);
  // v = wv*hT^T + bv  ([C,N] out)
  gemm_nt<1><<<dim3(NDIM / BN, CDIM / BM, BATCH), 256, 0, stream>>>(
      wvb, 0, hT, NC, vB, NC, bv, nullptr, 0, CDIM, NDIM, CDIM);

  if (ws_size >= base + (size_t)(4 * NN * 4) + (size_t)(4 * NN * 2)) {
    // Tier A (~489 MB): everything batched
    float* sc = (float*)dyn;
    unsigned short* at = (unsigned short*)(dyn + 4 * NN * 4);
    gemm_nt<2><<<dim3(NDIM / BN, NDIM / BM, BATCH), 256, 0, stream>>>(
        qT, NC, kT, NC, sc, NN, nullptr, nullptr, 0, NDIM, NDIM, CDIM);
    softmax_kernel<<<BATCH * NDIM, 256, 0, stream>>>(sc, at);
    gemm_nt<3><<<dim3(CDIM / BN, NDIM / BM, BATCH), 256, 0, stream>>>(
        at, NN, vB, NC, OT, NC, nullptr, nullptr, 0, NDIM, CDIM, NDIM);
  } else if (ws_size >= base + (size_t)(NN * 4) + (size_t)(4 * NN * 2)) {
    // Tier B (~287 MB): scores per batch, PV batched
    float* sc = (float*)dyn;
    unsigned short* at = (unsigned short*)(dyn + NN * 4);
    for (int b = 0; b < BATCH; ++b) {
      gemm_nt<2><<<dim3(NDIM / BN, NDIM / BM, 1), 256, 0, stream>>>(
          qT + b * NC, 0, kT + b * NC, 0, sc, 0, nullptr, nullptr, 0, NDIM, NDIM, CDIM);
      softmax_kernel<<<NDIM, 256, 0, stream>>>(sc, at + b * NN);
    }
    gemm_nt<3><<<dim3(CDIM / BN, NDIM / BM, BATCH), 256, 0, stream>>>(
        at, NN, vB, NC, OT, NC, nullptr, nullptr, 0, NDIM, CDIM, NDIM);
  } else {
    // Tier C (~187 MB): fully per-batch
    float* sc = (float*)dyn;
    unsigned short* at = (unsigned short*)(dyn + NN * 4);
    for (int b = 0; b < BATCH; ++b) {
      gemm_nt<2><<<dim3(NDIM / BN, NDIM / BM, 1), 256, 0, stream>>>(
          qT + b * NC, 0, kT + b * NC, 0, sc, 0, nullptr, nullptr, 0, NDIM, NDIM, CDIM);
      softmax_kernel<<<NDIM, 256, 0, stream>>>(sc, at);
      gemm_nt<3><<<dim3(CDIM / BN, NDIM / BM, 1), 256, 0, stream>>>(
          at, 0, vB + b * NC, 0, OT + b * NC, 0, nullptr, nullptr, 0, NDIM, CDIM, NDIM);
    }
  }

  // out = wp*OT^T + bp + x  (fp32 out, fused residual)
  gemm_nt<4><<<dim3(NDIM / BN, CDIM / BM, BATCH), 256, 0, stream>>>(
      wpb, 0, OT, NC, out, NC, bp, x, NC, CDIM, NDIM, CDIM);
}

// Round 3
// 477.545 us; speedup vs baseline: 1.7171x; 1.7171x over previous
//
#include <hip/hip_runtime.h>

#define CDIM 512
#define NDIM 4096
#define BATCH 4

using bf8v = __attribute__((ext_vector_type(8))) __bf16;
using f4v  = __attribute__((ext_vector_type(4))) float;
using h8v  = __attribute__((ext_vector_type(8))) _Float16;

typedef __attribute__((address_space(1))) unsigned int gu32;
typedef __attribute__((address_space(3))) unsigned int lu32;

static __device__ __forceinline__ unsigned short f2bf(float f) {
  unsigned int u = __float_as_uint(f);
  u += 0x7fffu + ((u >> 16) & 1u);   // round-to-nearest-even
  return (unsigned short)(u >> 16);
}

// ---------------- GN pass 1: per-(b,g) mean/rstd ----------------
__global__ __launch_bounds__(256) void gn_stats_kernel(
    const float* __restrict__ x, float* __restrict__ stats) {
  const int tid = threadIdx.x;
  const float4* xv = (const float4*)(x + (long)blockIdx.x * 65536);
  float s = 0.f, ss = 0.f;
  for (int i = tid; i < 16384; i += 256) {
    float4 d = xv[i];
    s  += d.x + d.y + d.z + d.w;
    ss += d.x * d.x + d.y * d.y + d.z * d.z + d.w * d.w;
  }
#pragma unroll
  for (int off = 32; off; off >>= 1) {
    s  += __shfl_down(s, off);
    ss += __shfl_down(ss, off);
  }
  __shared__ float red[8];
  if ((tid & 63) == 0) { red[tid >> 6] = s; red[4 + (tid >> 6)] = ss; }
  __syncthreads();
  if (tid == 0) {
    float S  = red[0] + red[1] + red[2] + red[3];
    float SS = red[4] + red[5] + red[6] + red[7];
    float mean = S * (1.f / 65536.f);
    float var  = SS * (1.f / 65536.f) - mean * mean;
    stats[blockIdx.x * 2]     = mean;
    stats[blockIdx.x * 2 + 1] = rsqrtf(var + 1e-6f);
  }
}

// ---------------- GN pass 2: normalize + transpose, fp32 [C,N] -> bf16 [N,C] ----------------
__global__ __launch_bounds__(256) void gn_transpose_kernel(
    const float* __restrict__ x, const float* __restrict__ gs,
    const float* __restrict__ gb, const float* __restrict__ stats,
    unsigned short* __restrict__ hT) {
  __shared__ float t[64][65];
  const int tid = threadIdx.x;
  const int b = blockIdx.z;
  const long bbx = (long)b * ((long)CDIM * NDIM);
  const int n0 = blockIdx.x * 64, c0 = blockIdx.y * 64;
  for (int k = 0; k < 4; ++k) {
    int it = tid + k * 256;
    int c = it >> 4, no = (it & 15) << 2;
    int ch = c0 + c;
    int g = ch >> 4;
    float mean = stats[(b * 32 + g) * 2];
    float rstd = stats[(b * 32 + g) * 2 + 1];
    float a  = rstd * gs[ch];
    float bb = gb[ch] - mean * a;
    float4 d = *(const float4*)&x[bbx + (long)ch * NDIM + n0 + no];
    t[no + 0][c] = d.x * a + bb;
    t[no + 1][c] = d.y * a + bb;
    t[no + 2][c] = d.z * a + bb;
    t[no + 3][c] = d.w * a + bb;
  }
  __syncthreads();
  const long bbh = (long)b * ((long)NDIM * CDIM);
  for (int k = 0; k < 2; ++k) {
    int it = tid + k * 256;
    int n = it >> 3, co = (it & 7) << 3;
    unsigned int ow[4];
#pragma unroll
    for (int j = 0; j < 4; ++j) {
      unsigned short lo = f2bf(t[n][co + 2 * j]);
      unsigned short hi = f2bf(t[n][co + 2 * j + 1]);
      ow[j] = (unsigned int)lo | ((unsigned int)hi << 16);
    }
    uint4 o; o.x = ow[0]; o.y = ow[1]; o.z = ow[2]; o.w = ow[3];
    *(uint4*)&hT[bbh + (long)(n0 + n) * CDIM + c0 + co] = o;
  }
}

// ---------------- fp32 -> bf16 convert (weights) ----------------
__global__ __launch_bounds__(256) void cvt_kernel(
    const float* __restrict__ src, unsigned short* __restrict__ dst, int n4) {
  int i = blockIdx.x * 256 + threadIdx.x;
  if (i >= n4) return;
  float4 d = ((const float4*)src)[i];
  ushort4 o;
  o.x = f2bf(d.x); o.y = f2bf(d.y); o.z = f2bf(d.z); o.w = f2bf(d.w);
  ((ushort4*)dst)[i] = o;
}

// ---------------- NT GEMM, m97-style staging ----------------
// C[M,Nn] = A[M,K] * B[Nn,K]^T, both operands bf16 K-contiguous.
// LDS: unpadded 64B rows (global_load_lds requires dst = wave-uniform base + lane*16).
// EPI: 0 = bf16 + bias[col]   (qT/kT)
//      1 = bf16 + bias[row]   (v)
//      2 = f16  * 512^-0.5    (scores)
//      3 = bf16 plain         (attn @ v -> OT)
//      4 = fp32 + bias[row] + residual X (proj -> d_out)
#define BM 128
#define BN 128
#define BK 32

template <int EPI>
__global__ __launch_bounds__(256) void gemm_nt(
    const unsigned short* __restrict__ A, long sA,
    const unsigned short* __restrict__ B, long sB,
    void* __restrict__ Cp, long sC,
    const float* __restrict__ bias,
    const float* __restrict__ X, long sX,
    int M, int Nn, int K) {
  __shared__ unsigned short As[BM * BK];   // 8 KB, row-major 64B rows
  __shared__ unsigned short Bs[BN * BK];   // 8 KB
  const int tid = threadIdx.x;
  const int z = blockIdx.z;
  A += (long)z * sA;
  B += (long)z * sB;
  const int m0 = blockIdx.y * BM;
  const int n0 = blockIdx.x * BN;
  const int lane = tid & 63;
  const int wv = tid >> 6;
  const int wm = (wv >> 1) << 6;
  const int wn = (wv & 1) << 6;
  const int l16 = lane & 15;
  const int quad = lane >> 4;
  const int lr = lane >> 2;          // row 0..15 within 16-row group
  const int lc = (lane & 3) << 3;    // k-offset in elems (16B chunks)

  f4v acc[4][4] = {};

  const unsigned short* Ab = A + (long)(m0 + wv * 16 + lr) * K + lc;
  const unsigned short* Bb = B + (long)(n0 + wv * 16 + lr) * K + lc;
  const long rowskip = 64L * K;

  for (int k0 = 0; k0 < K; k0 += BK) {
    // async global -> LDS staging (16B/lane, dst = base + lane*16)
    __builtin_amdgcn_global_load_lds((const gu32*)(Ab + k0),
        (lu32*)(As + wv * 512), 16, 0, 0);
    __builtin_amdgcn_global_load_lds((const gu32*)(Ab + k0 + rowskip),
        (lu32*)(As + 2048 + wv * 512), 16, 0, 0);
    __builtin_amdgcn_global_load_lds((const gu32*)(Bb + k0),
        (lu32*)(Bs + wv * 512), 16, 0, 0);
    __builtin_amdgcn_global_load_lds((const gu32*)(Bb + k0 + rowskip),
        (lu32*)(Bs + 2048 + wv * 512), 16, 0, 0);
    __syncthreads();   // drains vmcnt before barrier (compiler-enforced)
    bf8v af[4], bf[4];
#pragma unroll
    for (int t = 0; t < 4; ++t) {
      af[t] = *(const bf8v*)&As[(wm + t * 16 + l16) * BK + quad * 8];
      bf[t] = *(const bf8v*)&Bs[(wn + t * 16 + l16) * BK + quad * 8];
    }
#pragma unroll
    for (int tm = 0; tm < 4; ++tm)
#pragma unroll
      for (int tn = 0; tn < 4; ++tn)
        acc[tm][tn] = __builtin_amdgcn_mfma_f32_16x16x32_bf16(af[tm], bf[tn], acc[tm][tn], 0, 0, 0);
    __syncthreads();
  }

  // C/D layout (verified m89/m91): col = lane&15, row = quad*4 + reg
#pragma unroll
  for (int tm = 0; tm < 4; ++tm) {
#pragma unroll
    for (int tn = 0; tn < 4; ++tn) {
      const int col = n0 + wn + tn * 16 + l16;
#pragma unroll
      for (int r = 0; r < 4; ++r) {
        const int row = m0 + wm + tm * 16 + quad * 4 + r;
        float val = acc[tm][tn][r];
        if (EPI == 0) {
          val += bias[col];
          ((unsigned short*)Cp)[(long)z * sC + (long)row * Nn + col] = f2bf(val);
        } else if (EPI == 1) {
          val += bias[row];
          ((unsigned short*)Cp)[(long)z * sC + (long)row * Nn + col] = f2bf(val);
        } else if (EPI == 2) {
          ((_Float16*)Cp)[(long)z * sC + (long)row * Nn + col] =
              (_Float16)(val * 0.044194173824159216f);
        } else if (EPI == 3) {
          ((unsigned short*)Cp)[(long)z * sC + (long)row * Nn + col] = f2bf(val);
        } else {
          ((float*)Cp)[(long)z * sC + (long)row * Nn + col] =
              val + bias[row] + X[(long)z * sX + (long)row * Nn + col];
        }
      }
    }
  }
}

// ---------------- In-place row softmax: f16 scores row -> bf16 attn row ----------------
// Same addresses; all loads complete before the first __syncthreads, writes after.
__global__ __launch_bounds__(256) void softmax_kernel(unsigned short* __restrict__ S) {
  const int tid = threadIdx.x;
  unsigned short* row = S + (long)blockIdx.x * NDIM;
  float v[16];
  float mx = -3.4e38f;
#pragma unroll
  for (int it = 0; it < 2; ++it) {
    h8v d = ((const h8v*)row)[it * 256 + tid];
#pragma unroll
    for (int j = 0; j < 8; ++j) {
      float f = (float)d[j];
      v[it * 8 + j] = f;
      mx = fmaxf(mx, f);
    }
  }
#pragma unroll
  for (int off = 32; off; off >>= 1) mx = fmaxf(mx, __shfl_xor(mx, off));
  __shared__ float red[8];
  if ((tid & 63) == 0) red[tid >> 6] = mx;
  __syncthreads();
  mx = fmaxf(fmaxf(red[0], red[1]), fmaxf(red[2], red[3]));
  float sum = 0.f;
#pragma unroll
  for (int j = 0; j < 16; ++j) {
    v[j] = __expf(v[j] - mx);
    sum += v[j];
  }
#pragma unroll
  for (int off = 32; off; off >>= 1) sum += __shfl_xor(sum, off);
  if ((tid & 63) == 0) red[4 + (tid >> 6)] = sum;
  __syncthreads();
  sum = red[4] + red[5] + red[6] + red[7];
  const float inv = 1.f / sum;
#pragma unroll
  for (int it = 0; it < 2; ++it) {
    unsigned int ow[4];
#pragma unroll
    for (int j = 0; j < 4; ++j) {
      unsigned short lo = f2bf(v[it * 8 + 2 * j] * inv);
      unsigned short hi = f2bf(v[it * 8 + 2 * j + 1] * inv);
      ow[j] = (unsigned int)lo | ((unsigned int)hi << 16);
    }
    uint4 o; o.x = ow[0]; o.y = ow[1]; o.z = ow[2]; o.w = ow[3];
    ((uint4*)row)[it * 256 + tid] = o;
  }
}

extern "C" void kernel_launch(void* const* d_in, const int* in_sizes, int n_in,
                              void* d_out, int out_size, void* d_ws, size_t ws_size,
                              hipStream_t stream) {
  (void)in_sizes; (void)n_in; (void)out_size;
  const float* x  = (const float*)d_in[0];
  const float* gs = (const float*)d_in[1];
  const float* gb = (const float*)d_in[2];
  const float* wq = (const float*)d_in[3];
  const float* bq = (const float*)d_in[4];
  const float* wk = (const float*)d_in[5];
  const float* bk = (const float*)d_in[6];
  const float* wv = (const float*)d_in[7];
  const float* bv = (const float*)d_in[8];
  const float* wp = (const float*)d_in[9];
  const float* bp = (const float*)d_in[10];
  float* out = (float*)d_out;

  char* ws = (char*)d_ws;
  const long NC  = (long)NDIM * CDIM;        // per-batch [N,C] elems = 2,097,152
  const long BUF = NC * 2 * BATCH;           // one [B,N,C] bf16 buffer = 16,777,216 B
  const long NN  = (long)NDIM * NDIM;        // per-batch scores elems

  // Layout (tight, aliased):
  //   [0, BUF)        hT, later OT (hT dead after v GEMM; OT written by PV after)
  //   [BUF, 2BUF)     qT, later wpb (qT dead after last scores GEMM)
  //   [2BUF, 3BUF)    kT
  //   [3BUF, 4BUF)    vB
  //   [4BUF, ...)     sc16: f16 scores -> bf16 attn in place.
  //                   Head of sc16 doubles as wqb/wkb/wvb/stats (dead before scores).
  unsigned short* hT  = (unsigned short*)(ws);
  unsigned short* OT  = hT;
  unsigned short* qT  = (unsigned short*)(ws + BUF);
  unsigned short* kT  = (unsigned short*)(ws + BUF * 2);
  unsigned short* vB  = (unsigned short*)(ws + BUF * 3);
  unsigned short* sc  = (unsigned short*)(ws + BUF * 4);
  unsigned short* wqb = sc;
  unsigned short* wkb = (unsigned short*)(ws + BUF * 4 + 524288);
  unsigned short* wvb = (unsigned short*)(ws + BUF * 4 + 1048576);
  float* stats        = (float*)(ws + BUF * 4 + 1572864);
  unsigned short* wpb = qT;  // converted after qT is dead

  gn_stats_kernel<<<BATCH * 32, 256, 0, stream>>>(x, stats);
  gn_transpose_kernel<<<dim3(NDIM / 64, CDIM / 64, BATCH), 256, 0, stream>>>(x, gs, gb, stats, hT);
  cvt_kernel<<<256, 256, 0, stream>>>(wq, wqb, 65536);
  cvt_kernel<<<256, 256, 0, stream>>>(wk, wkb, 65536);
  cvt_kernel<<<256, 256, 0, stream>>>(wv, wvb, 65536);

  // qT = hT*wq^T + bq ; kT = hT*wk^T + bk  ([N,C] out)
  gemm_nt<0><<<dim3(CDIM / BN, NDIM / BM, BATCH), 256, 0, stream>>>(
      hT, NC, wqb, 0, qT, NC, bq, nullptr, 0, NDIM, CDIM, CDIM);
  gemm_nt<0><<<dim3(CDIM / BN, NDIM / BM, BATCH), 256, 0, stream>>>(
      hT, NC, wkb, 0, kT, NC, bk, nullptr, 0, NDIM, CDIM, CDIM);
  // v = wv*hT^T + bv  ([C,N] out)
  gemm_nt<1><<<dim3(NDIM / BN, CDIM / BM, BATCH), 256, 0, stream>>>(
      wvb, 0, hT, NC, vB, NC, bv, nullptr, 0, CDIM, NDIM, CDIM);

  if (ws_size >= (size_t)(BUF * 4) + (size_t)(NN * 2) * BATCH) {
    // Primary (192 MiB): fully batched attention.
    gemm_nt<2><<<dim3(NDIM / BN, NDIM / BM, BATCH), 256, 0, stream>>>(
        qT, NC, kT, NC, sc, NN, nullptr, nullptr, 0, NDIM, NDIM, CDIM);
    softmax_kernel<<<BATCH * NDIM, 256, 0, stream>>>(sc);
    gemm_nt<3><<<dim3(CDIM / BN, NDIM / BM, BATCH), 256, 0, stream>>>(
        sc, NN, vB, NC, OT, NC, nullptr, nullptr, 0, NDIM, CDIM, NDIM);
  } else {
    // Fallback (~101 MB): per-batch rounds.
    for (int b = 0; b < BATCH; ++b) {
      gemm_nt<2><<<dim3(NDIM / BN, NDIM / BM, 1), 256, 0, stream>>>(
          qT + b * NC, 0, kT + b * NC, 0, sc, 0, nullptr, nullptr, 0, NDIM, NDIM, CDIM);
      softmax_kernel<<<NDIM, 256, 0, stream>>>(sc);
      gemm_nt<3><<<dim3(CDIM / BN, NDIM / BM, 1), 256, 0, stream>>>(
          sc, 0, vB + b * NC, 0, OT + b * NC, 0, nullptr, nullptr, 0, NDIM, CDIM, NDIM);
    }
  }

  // out = wp*OT^T + bp + x  (fp32 out, fused residual); wpb overlays dead qT
  cvt_kernel<<<256, 256, 0, stream>>>(wp, wpb, 65536);
  gemm_nt<4><<<dim3(NDIM / BN, CDIM / BM, BATCH), 256, 0, stream>>>(
      wpb, 0, OT, NC, out, NC, bp, x, NC, CDIM, NDIM, CDIM);
}

// Round 4
// 425.588 us; speedup vs baseline: 1.9267x; 1.1221x over previous
//
#include <hip/hip_runtime.h>

#define CDIM 512
#define NDIM 4096
#define BATCH 4

using bf8v = __attribute__((ext_vector_type(8))) __bf16;
using f4v  = __attribute__((ext_vector_type(4))) float;
using h8v  = __attribute__((ext_vector_type(8))) _Float16;

typedef __attribute__((address_space(1))) unsigned int gu32;
typedef __attribute__((address_space(3))) unsigned int lu32;

static __device__ __forceinline__ unsigned short f2bf(float f) {
  unsigned int u = __float_as_uint(f);
  u += 0x7fffu + ((u >> 16) & 1u);   // round-to-nearest-even
  return (unsigned short)(u >> 16);
}

// ---------------- GN pass 1: per-(b,g) mean/rstd ----------------
__global__ __launch_bounds__(256) void gn_stats_kernel(
    const float* __restrict__ x, float* __restrict__ stats) {
  const int tid = threadIdx.x;
  const float4* xv = (const float4*)(x + (long)blockIdx.x * 65536);
  float s = 0.f, ss = 0.f;
  for (int i = tid; i < 16384; i += 256) {
    float4 d = xv[i];
    s  += d.x + d.y + d.z + d.w;
    ss += d.x * d.x + d.y * d.y + d.z * d.z + d.w * d.w;
  }
#pragma unroll
  for (int off = 32; off; off >>= 1) {
    s  += __shfl_down(s, off);
    ss += __shfl_down(ss, off);
  }
  __shared__ float red[8];
  if ((tid & 63) == 0) { red[tid >> 6] = s; red[4 + (tid >> 6)] = ss; }
  __syncthreads();
  if (tid == 0) {
    float S  = red[0] + red[1] + red[2] + red[3];
    float SS = red[4] + red[5] + red[6] + red[7];
    float mean = S * (1.f / 65536.f);
    float var  = SS * (1.f / 65536.f) - mean * mean;
    stats[blockIdx.x * 2]     = mean;
    stats[blockIdx.x * 2 + 1] = rsqrtf(var + 1e-6f);
  }
}

// ---------------- GN pass 2: normalize + transpose, fp32 [C,N] -> bf16 [N,C] ----------------
__global__ __launch_bounds__(256) void gn_transpose_kernel(
    const float* __restrict__ x, const float* __restrict__ gs,
    const float* __restrict__ gb, const float* __restrict__ stats,
    unsigned short* __restrict__ hT) {
  __shared__ float t[64][65];
  const int tid = threadIdx.x;
  const int b = blockIdx.z;
  const long bbx = (long)b * ((long)CDIM * NDIM);
  const int n0 = blockIdx.x * 64, c0 = blockIdx.y * 64;
  for (int k = 0; k < 4; ++k) {
    int it = tid + k * 256;
    int c = it >> 4, no = (it & 15) << 2;
    int ch = c0 + c;
    int g = ch >> 4;
    float mean = stats[(b * 32 + g) * 2];
    float rstd = stats[(b * 32 + g) * 2 + 1];
    float a  = rstd * gs[ch];
    float bb = gb[ch] - mean * a;
    float4 d = *(const float4*)&x[bbx + (long)ch * NDIM + n0 + no];
    t[no + 0][c] = d.x * a + bb;
    t[no + 1][c] = d.y * a + bb;
    t[no + 2][c] = d.z * a + bb;
    t[no + 3][c] = d.w * a + bb;
  }
  __syncthreads();
  const long bbh = (long)b * ((long)NDIM * CDIM);
  for (int k = 0; k < 2; ++k) {
    int it = tid + k * 256;
    int n = it >> 3, co = (it & 7) << 3;
    unsigned int ow[4];
#pragma unroll
    for (int j = 0; j < 4; ++j) {
      unsigned short lo = f2bf(t[n][co + 2 * j]);
      unsigned short hi = f2bf(t[n][co + 2 * j + 1]);
      ow[j] = (unsigned int)lo | ((unsigned int)hi << 16);
    }
    uint4 o; o.x = ow[0]; o.y = ow[1]; o.z = ow[2]; o.w = ow[3];
    *(uint4*)&hT[bbh + (long)(n0 + n) * CDIM + c0 + co] = o;
  }
}

// ---------------- fp32 -> bf16 convert (weights) ----------------
__global__ __launch_bounds__(256) void cvt_kernel(
    const float* __restrict__ src, unsigned short* __restrict__ dst, int n4) {
  int i = blockIdx.x * 256 + threadIdx.x;
  if (i >= n4) return;
  float4 d = ((const float4*)src)[i];
  ushort4 o;
  o.x = f2bf(d.x); o.y = f2bf(d.y); o.z = f2bf(d.z); o.w = f2bf(d.w);
  ((ushort4*)dst)[i] = o;
}

// ---------------- concat 2x512 fp32 bias -> 1024 ----------------
__global__ __launch_bounds__(256) void concat_bias_kernel(
    const float* __restrict__ a, const float* __restrict__ b, float* __restrict__ dst) {
  int i = blockIdx.x * 256 + threadIdx.x;
  if (i < 512) dst[i] = a[i];
  else if (i < 1024) dst[i] = b[i - 512];
}

// ---------------- NT GEMM, BK=64, XOR-swizzled LDS, global_load_lds staging ----------------
// C[M,Nn] = A[M,K] * B[Nn,K]^T, bf16 operands, row strides lA/lB.
// LDS rows = 128B (8 chunks of 16B); chunk c of row r stored at position c^(r&7)
// -> 2-way-max bank aliasing on ds_read_b128 (free) while keeping the
//    wave-uniform-base + lane*16 dst required by global_load_lds (src is per-lane swizzled).
// EPI: 0 = bf16 + bias[col]; 1 = bf16 + bias[row]; 2 = f16 * 512^-0.5;
//      3 = bf16 plain; 4 = fp32 + bias[row] + residual X.
// SWZ: 0 = none; 1 = PV XCD-grouping (flat grid, conceptual 4x32xZ);
//      2 = scores group-raster (flat grid, conceptual 32x32xZ).
#define BM 128
#define BN 128
#define BK 64

template <int EPI, int SWZ>
__global__ __launch_bounds__(256) void gemm_nt(
    const unsigned short* __restrict__ A, long sA, int lA,
    const unsigned short* __restrict__ B, long sB, int lB,
    void* __restrict__ Cp, long sC,
    const float* __restrict__ bias,
    const float* __restrict__ X, long sX,
    int Nn, int K) {
  __shared__ unsigned short As[BM * BK];   // 16 KB
  __shared__ unsigned short Bs[BN * BK];   // 16 KB
  int bx, by, bz;
  if (SWZ == 0) {
    bx = blockIdx.x; by = blockIdx.y; bz = blockIdx.z;
  } else if (SWZ == 1) {
    // groups of 4 col-blocks (same attn row-block) share flat%8 -> same XCD
    int flat = blockIdx.x;
    int q = flat >> 5, r = flat & 31;
    bx = r >> 3;
    int g = q * 8 + (r & 7);
    by = g & 31; bz = g >> 5;
  } else {
    int flat = blockIdx.x;
    bz = flat >> 10;
    int f = flat & 1023;
    by = (f & 7) + ((f >> 8) << 3);
    bx = (f >> 3) & 31;
  }
  const int tid = threadIdx.x;
  A += (long)bz * sA;
  B += (long)bz * sB;
  const int m0 = by * BM;
  const int n0 = bx * BN;
  const int lane = tid & 63;
  const int wv = tid >> 6;
  const int wm = (wv >> 1) << 6;
  const int wn = (wv & 1) << 6;
  const int l16 = lane & 15;
  const int quad = lane >> 4;
  const int sw = l16 & 7;            // fragment-read swizzle key (= row&7)
  const int r8 = lane >> 3;          // staging: row within 8-row group
  const int c8 = lane & 7;           // staging: chunk slot
  const int csw = (c8 ^ r8) << 3;    // swizzled source chunk, in elems

  f4v acc[4][4] = {};

  const unsigned short* Ag = A + (long)(m0 + wv * 32 + r8) * lA + csw;
  const unsigned short* Bg = B + (long)(n0 + wv * 32 + r8) * lB + csw;
  unsigned short* Asl = As + wv * 32 * BK;
  unsigned short* Bsl = Bs + wv * 32 * BK;

  for (int k0 = 0; k0 < K; k0 += BK) {
#pragma unroll
    for (int i = 0; i < 4; ++i) {
      __builtin_amdgcn_global_load_lds((const gu32*)(Ag + (long)i * 8 * lA + k0),
          (lu32*)(Asl + i * 512), 16, 0, 0);
      __builtin_amdgcn_global_load_lds((const gu32*)(Bg + (long)i * 8 * lB + k0),
          (lu32*)(Bsl + i * 512), 16, 0, 0);
    }
    __syncthreads();
    bf8v af[2][4], bf[2][4];
#pragma unroll
    for (int kk = 0; kk < 2; ++kk) {
#pragma unroll
      for (int t = 0; t < 4; ++t) {
        int ra = wm + t * 16 + l16;
        int rb = wn + t * 16 + l16;
        af[kk][t] = *(const bf8v*)&As[ra * BK + ((((kk << 2) + quad) ^ sw) << 3)];
        bf[kk][t] = *(const bf8v*)&Bs[rb * BK + ((((kk << 2) + quad) ^ sw) << 3)];
      }
    }
#pragma unroll
    for (int kk = 0; kk < 2; ++kk)
#pragma unroll
      for (int tm = 0; tm < 4; ++tm)
#pragma unroll
        for (int tn = 0; tn < 4; ++tn)
          acc[tm][tn] = __builtin_amdgcn_mfma_f32_16x16x32_bf16(
              af[kk][tm], bf[kk][tn], acc[tm][tn], 0, 0, 0);
    __syncthreads();
  }

  // C/D layout (verified m89/m91): col = lane&15, row = quad*4 + reg
#pragma unroll
  for (int tm = 0; tm < 4; ++tm) {
#pragma unroll
    for (int tn = 0; tn < 4; ++tn) {
      const int col = n0 + wn + tn * 16 + l16;
#pragma unroll
      for (int r = 0; r < 4; ++r) {
        const int row = m0 + wm + tm * 16 + quad * 4 + r;
        float val = acc[tm][tn][r];
        if (EPI == 0) {
          val += bias[col];
          ((unsigned short*)Cp)[(long)bz * sC + (long)row * Nn + col] = f2bf(val);
        } else if (EPI == 1) {
          val += bias[row];
          ((unsigned short*)Cp)[(long)bz * sC + (long)row * Nn + col] = f2bf(val);
        } else if (EPI == 2) {
          ((_Float16*)Cp)[(long)bz * sC + (long)row * Nn + col] =
              (_Float16)(val * 0.044194173824159216f);
        } else if (EPI == 3) {
          ((unsigned short*)Cp)[(long)bz * sC + (long)row * Nn + col] = f2bf(val);
        } else {
          ((float*)Cp)[(long)bz * sC + (long)row * Nn + col] =
              val + bias[row] + X[(long)bz * sX + (long)row * Nn + col];
        }
      }
    }
  }
}

// ---------------- In-place row softmax: f16 scores row -> bf16 attn row ----------------
__global__ __launch_bounds__(256) void softmax_kernel(unsigned short* __restrict__ S) {
  const int tid = threadIdx.x;
  unsigned short* row = S + (long)blockIdx.x * NDIM;
  float v[16];
  float mx = -3.4e38f;
#pragma unroll
  for (int it = 0; it < 2; ++it) {
    h8v d = ((const h8v*)row)[it * 256 + tid];
#pragma unroll
    for (int j = 0; j < 8; ++j) {
      float f = (float)d[j];
      v[it * 8 + j] = f;
      mx = fmaxf(mx, f);
    }
  }
#pragma unroll
  for (int off = 32; off; off >>= 1) mx = fmaxf(mx, __shfl_xor(mx, off));
  __shared__ float red[8];
  if ((tid & 63) == 0) red[tid >> 6] = mx;
  __syncthreads();
  mx = fmaxf(fmaxf(red[0], red[1]), fmaxf(red[2], red[3]));
  float sum = 0.f;
#pragma unroll
  for (int j = 0; j < 16; ++j) {
    v[j] = __expf(v[j] - mx);
    sum += v[j];
  }
#pragma unroll
  for (int off = 32; off; off >>= 1) sum += __shfl_xor(sum, off);
  if ((tid & 63) == 0) red[4 + (tid >> 6)] = sum;
  __syncthreads();
  sum = red[4] + red[5] + red[6] + red[7];
  const float inv = 1.f / sum;
#pragma unroll
  for (int it = 0; it < 2; ++it) {
    unsigned int ow[4];
#pragma unroll
    for (int j = 0; j < 4; ++j) {
      unsigned short lo = f2bf(v[it * 8 + 2 * j] * inv);
      unsigned short hi = f2bf(v[it * 8 + 2 * j + 1] * inv);
      ow[j] = (unsigned int)lo | ((unsigned int)hi << 16);
    }
    uint4 o; o.x = ow[0]; o.y = ow[1]; o.z = ow[2]; o.w = ow[3];
    ((uint4*)row)[it * 256 + tid] = o;
  }
}

extern "C" void kernel_launch(void* const* d_in, const int* in_sizes, int n_in,
                              void* d_out, int out_size, void* d_ws, size_t ws_size,
                              hipStream_t stream) {
  (void)in_sizes; (void)n_in; (void)out_size;
  const float* x  = (const float*)d_in[0];
  const float* gs = (const float*)d_in[1];
  const float* gb = (const float*)d_in[2];
  const float* wq = (const float*)d_in[3];
  const float* bq = (const float*)d_in[4];
  const float* wk = (const float*)d_in[5];
  const float* bk = (const float*)d_in[6];
  const float* wv = (const float*)d_in[7];
  const float* bv = (const float*)d_in[8];
  const float* wp = (const float*)d_in[9];
  const float* bp = (const float*)d_in[10];
  float* out = (float*)d_out;

  char* ws = (char*)d_ws;
  const long NC  = (long)NDIM * CDIM;        // per-batch [N,C] elems
  const long NQK = (long)NDIM * 1024;        // per-batch [N,1024] elems
  const long BUF = NC * 2 * BATCH;           // [B,N,C] bf16 buffer = 16,777,216 B
  const long NN  = (long)NDIM * NDIM;

  // Layout (aliased):
  //   [0, BUF)        hT, later OT
  //   [BUF, 3BUF)     qkT [B,N,1024]; later wpb overlays its head
  //   [3BUF, 4BUF)    vB [B,C,N]
  //   [4BUF, ...)     sc: f16 scores -> bf16 attn in place; head doubles as
  //                   wqkb/wvb/bqk/stats (all dead before scores GEMM writes)
  unsigned short* hT   = (unsigned short*)(ws);
  unsigned short* OT   = hT;
  unsigned short* qkT  = (unsigned short*)(ws + BUF);
  unsigned short* vB   = (unsigned short*)(ws + BUF * 3);
  unsigned short* sc   = (unsigned short*)(ws + BUF * 4);
  unsigned short* wqkb = sc;                                   // 1 MB
  unsigned short* wvb  = (unsigned short*)(ws + BUF * 4 + 1048576);
  float* bqk           = (float*)(ws + BUF * 4 + 1572864);
  float* stats         = (float*)(ws + BUF * 4 + 1581056);
  unsigned short* wpb  = qkT;  // overlays dead qkT for final proj

  gn_stats_kernel<<<BATCH * 32, 256, 0, stream>>>(x, stats);
  gn_transpose_kernel<<<dim3(NDIM / 64, CDIM / 64, BATCH), 256, 0, stream>>>(x, gs, gb, stats, hT);
  cvt_kernel<<<256, 256, 0, stream>>>(wq, wqkb, 65536);
  cvt_kernel<<<256, 256, 0, stream>>>(wk, wqkb + 262144, 65536);
  cvt_kernel<<<256, 256, 0, stream>>>(wv, wvb, 65536);
  concat_bias_kernel<<<4, 256, 0, stream>>>(bq, bk, bqk);

  // qkT = hT * [wq;wk]^T + bqk  ([N,1024])
  gemm_nt<0, 0><<<dim3(1024 / BN, NDIM / BM, BATCH), 256, 0, stream>>>(
      hT, NC, CDIM, wqkb, 0, CDIM, qkT, NQK, bqk, nullptr, 0, 1024, CDIM);
  // v = wv * hT^T + bv  ([C,N])
  gemm_nt<1, 0><<<dim3(NDIM / BN, CDIM / BM, BATCH), 256, 0, stream>>>(
      wvb, 0, CDIM, hT, NC, CDIM, vB, NC, bv, nullptr, 0, NDIM, CDIM);

  if (ws_size >= (size_t)(BUF * 4) + (size_t)(NN * 2) * BATCH) {
    // Primary (192 MiB): fully batched attention.
    gemm_nt<2, 2><<<dim3(1024 * BATCH, 1, 1), 256, 0, stream>>>(
        qkT, NQK, 1024, qkT + 512, NQK, 1024, sc, NN, nullptr, nullptr, 0, NDIM, CDIM);
    softmax_kernel<<<BATCH * NDIM, 256, 0, stream>>>(sc);
    gemm_nt<3, 1><<<dim3(512, 1, 1), 256, 0, stream>>>(
        sc, NN, NDIM, vB, NC, NDIM, OT, NC, nullptr, nullptr, 0, CDIM, NDIM);
  } else {
    // Fallback (~101 MB): per-batch rounds.
    for (int b = 0; b < BATCH; ++b) {
      gemm_nt<2, 2><<<dim3(1024, 1, 1), 256, 0, stream>>>(
          qkT + b * NQK, 0, 1024, qkT + b * NQK + 512, 0, 1024, sc, 0,
          nullptr, nullptr, 0, NDIM, CDIM);
      softmax_kernel<<<NDIM, 256, 0, stream>>>(sc);
      gemm_nt<3, 1><<<dim3(128, 1, 1), 256, 0, stream>>>(
          sc, 0, NDIM, vB + b * NC, 0, NDIM, OT + b * NC, 0,
          nullptr, nullptr, 0, CDIM, NDIM);
    }
  }

  // out = wp * OT^T + bp + x  (fp32 out, fused residual); wpb overlays dead qkT
  cvt_kernel<<<256, 256, 0, stream>>>(wp, wpb, 65536);
  gemm_nt<4, 0><<<dim3(NDIM / BN, CDIM / BM, BATCH), 256, 0, stream>>>(
      wpb, 0, CDIM, OT, NC, CDIM, out, NC, bp, x, NC, NDIM, CDIM);
}